// Round 5
// baseline (120.695 us; speedup 1.0000x reference)
//
#include <hip/hip_runtime.h>
#include <hip/hip_bf16.h>
#include <stdint.h>

typedef __attribute__((ext_vector_type(8))) short short8;
typedef __attribute__((ext_vector_type(4))) float floatx4;
typedef __attribute__((ext_vector_type(4))) int intx4;

// ---------------------------------------------------------------------------
// Threefry-2x32 (20 rounds), bit-exact vs JAX (verified r2: absmax 0.0).
// ---------------------------------------------------------------------------
__device__ __forceinline__ void threefry2x32(uint32_t k0, uint32_t k1,
                                             uint32_t& x0, uint32_t& x1) {
  const uint32_t ks2 = k0 ^ k1 ^ 0x1BD11BDAu;
  uint32_t ks[3] = {k0, k1, ks2};
  const int rot[8] = {13, 15, 26, 6, 17, 29, 16, 24};
  x0 += ks[0];
  x1 += ks[1];
#pragma unroll
  for (int i = 0; i < 5; ++i) {
#pragma unroll
    for (int j = 0; j < 4; ++j) {
      const int r = rot[(i & 1) * 4 + j];
      x0 += x1;
      x1 = (x1 << r) | (x1 >> (32 - r));
      x1 ^= x0;
    }
    x0 += ks[(i + 1) % 3];
    x1 += ks[(i + 2) % 3] + (uint32_t)(i + 1);
  }
}

__device__ __forceinline__ float dropmask(int core, int e, float v) {
  uint32_t f0 = 0u, f1 = (uint32_t)core;
  threefry2x32(0u, 42u, f0, f1);
  uint32_t a = 0u, b = (uint32_t)e;
  threefry2x32(f0, f1, a, b);
  uint32_t bits = a ^ b;
  float u = __uint_as_float((bits >> 9) | 0x3F800000u) - 1.0f;
  float m = (u < 0.8f) ? 1.0f : 0.0f;
  return v * m / 0.8f;
}

__device__ __forceinline__ unsigned short f2bf(float f) {  // RNE
  uint32_t u = __float_as_uint(f);
  uint32_t r = u + 0x7fffu + ((u >> 16) & 1u);
  return (unsigned short)(r >> 16);
}

union B2I { __hip_bfloat162 b; int i; };
__device__ __forceinline__ int pk_bf16(float lo, float hi) {
  B2I u;
  u.b = __float22bfloat162_rn(make_float2(lo, hi));
  return u.i;
}
union Frag { intx4 i; short8 s; };

// ---------------------------------------------------------------------------
// Prep: masked bf16 B matrices, pre-swizzled into MFMA B-fragment order
// (verified r3/r4). stage1: k = c*32+q*8+j (c<16). stage2: t=45q+c, m=t/5,
// nk=8*(t%5)+j (c<45, K'=1440, zeros for nk>=36 or invalid col).
// Also zero-inits out (linear_kernel accumulates with atomics).
// ---------------------------------------------------------------------------
__global__ void prep_kernel(const float* __restrict__ eps0,
                            const float* __restrict__ eps1,
                            unsigned short* __restrict__ bsw1,
                            unsigned short* __restrict__ bsw2,
                            float* __restrict__ out) {
  int idx = blockIdx.x * 256 + threadIdx.x;  // grid exactly 31232
  if (idx < 1280) out[idx] = 0.0f;
  if (idx < 8192) {
    int j = idx & 7, L = (idx >> 3) & 63, c = idx >> 9;
    int o = L & 15, q = L >> 4;
    int k = c * 32 + q * 8 + j;
    float v = 0.0f;
    if (o < 6) {
      int e = o * 512 + k;
      v = dropmask(0, e, eps0[e]);
    }
    bsw1[idx] = f2bf(v);
  } else {
    int t2 = idx - 8192;  // < 23040 = 45*512
    int j = t2 & 7, L = (t2 >> 3) & 63, c = t2 >> 9;
    int o = L & 15, q = L >> 4;
    int t = 45 * q + c;
    int m = t / 5, nk = 8 * (t % 5) + j;
    float v = 0.0f;
    if (o < 10 && nk < 36) {
      int e = o * 1296 + m * 36 + nk;
      v = dropmask(1, e, eps1[e]);
    }
    bsw2[t2] = f2bf(v);
  }
}

// 6-way / 4-way selects, cndmask chains (works with dynamic k, no scratch)
__device__ __forceinline__ float sel6(const float a[6], int k) {
  float r = a[0];
  r = (k == 1) ? a[1] : r;
  r = (k == 2) ? a[2] : r;
  r = (k == 3) ? a[3] : r;
  r = (k == 4) ? a[4] : r;
  r = (k == 5) ? a[5] : r;
  return r;
}
__device__ __forceinline__ float sel4(const float a[4], int k) {
  float r = a[0];
  r = (k == 1) ? a[1] : r;
  r = (k == 2) ? a[2] : r;
  r = (k == 3) ? a[3] : r;
  return r;
}

// ---------------------------------------------------------------------------
// Stage 1 via MFMA, B staged in LDS (16 KB). K-loop: outer cc (unroll 1) x
// inner 4 chunks; __launch_bounds__(256,2) caps VGPR at 256 -> no spill.
// ---------------------------------------------------------------------------
__global__ __launch_bounds__(256, 2) void stage1_mfma(
    const float* __restrict__ x, const unsigned short* __restrict__ bsw1,
    float* __restrict__ h) {
  __shared__ unsigned short Bs[8192];
  {
    const intx4* src = (const intx4*)bsw1;
    intx4* dst = (intx4*)Bs;
#pragma unroll
    for (int t = 0; t < 4; ++t)
      dst[threadIdx.x + 256 * t] = src[threadIdx.x + 256 * t];
  }
  __syncthreads();

  const int lane = threadIdx.x & 63;
  const int wave = (blockIdx.x * 256 + threadIdx.x) >> 6;  // 0..5407
  const int col = lane & 15, q = lane >> 4;
  const int pid = wave * 16 + col;
  const int b = pid / 676;
  const int rem = pid - b * 676;
  const int ii = rem / 26;
  const int jj = rem - ii * 26;

  const float2* x2 = (const float2*)x;
  float xv[9][2];
#pragma unroll
  for (int di = 0; di < 3; ++di)
#pragma unroll
    for (int dj = 0; dj < 3; ++dj) {
      float2 v = x2[(b * 28 + ii + di) * 28 + (jj + dj)];
      xv[di * 3 + dj][0] = v.x;
      xv[di * 3 + dj][1] = v.y;
    }

  float w3[8];
#pragma unroll
  for (int j = 0; j < 8; ++j)
    w3[j] = xv[6][(j >> 2) & 1] * xv[7][(j >> 1) & 1] * xv[8][j & 1];

  // chunk c -> u = 4c+q: c bits from pixels 0..3, q bits from pixels 4,5
  const float wq = xv[4][(q >> 1) & 1] * xv[5][q & 1];
  float t01[4], t23[4];
#pragma unroll
  for (int a = 0; a < 2; ++a)
#pragma unroll
    for (int d = 0; d < 2; ++d) {
      t01[a * 2 + d] = xv[0][a] * xv[1][d];
      t23[a * 2 + d] = xv[2][a] * xv[3][d] * wq;
    }

  floatx4 acc0 = {0.f, 0.f, 0.f, 0.f};
  floatx4 acc1 = {0.f, 0.f, 0.f, 0.f};
  const unsigned short* bp = Bs + lane * 8;
#pragma unroll 1
  for (int cc = 0; cc < 4; ++cc) {  // c = 4*cc + e
    const float tA = sel4(t01, cc);
    const unsigned short* bpc = bp + cc * 4 * 512;
#pragma unroll
    for (int e = 0; e < 4; ++e) {
      Frag bf;
      bf.i = *(const intx4*)(bpc + e * 512);
      const float w = tA * t23[e];
      Frag af;
      af.i.x = pk_bf16(w * w3[0], w * w3[1]);
      af.i.y = pk_bf16(w * w3[2], w * w3[3]);
      af.i.z = pk_bf16(w * w3[4], w * w3[5]);
      af.i.w = pk_bf16(w * w3[6], w * w3[7]);
      if (e & 1)
        acc1 = __builtin_amdgcn_mfma_f32_16x16x32_bf16(af.s, bf.s, acc1, 0, 0, 0);
      else
        acc0 = __builtin_amdgcn_mfma_f32_16x16x32_bf16(af.s, bf.s, acc0, 0, 0, 0);
    }
  }
  const floatx4 acc = acc0 + acc1;
  if (col < 6) {
#pragma unroll
    for (int r = 0; r < 4; ++r) h[(wave * 16 + q * 4 + r) * 6 + col] = acc[r];
  }
}

// ---------------------------------------------------------------------------
// Stage 2 via MFMA, B staged in LDS (46080 B, 3 blocks/CU). K'=1440.
// Outer d=0..8 (unroll 1, P01 inline via sel6) x inner e=0..4 (n0=8e
// compile-time). __launch_bounds__(256,2) -> no spill.
// ---------------------------------------------------------------------------
__global__ __launch_bounds__(256, 2) void stage2_mfma(
    const float* __restrict__ h, const unsigned short* __restrict__ bsw2,
    float* __restrict__ flat) {
  __shared__ unsigned short Bs[23040];
  {
    const intx4* src = (const intx4*)bsw2;
    intx4* dst = (intx4*)Bs;
    for (int t = threadIdx.x; t < 2880; t += 256) dst[t] = src[t];
  }
  __syncthreads();

  const int lane = threadIdx.x & 63;
  const int wave = (blockIdx.x * 256 + threadIdx.x) >> 6;  // 0..4999
  const int col = lane & 15, q = lane >> 4;
  const int pid = wave * 16 + col;
  const int b = pid / 625;
  const int rem = pid - b * 625;
  const int ii = rem / 25;
  const int jj = rem - ii * 25;

  const float* hp = h + ((b * 26 + ii) * 26 + jj) * 6;
  float h00[6], h01[6], h10[6], h11[6];
  const float2* hp2a = (const float2*)(hp);
  const float2* hp2b = (const float2*)(hp + 156);
#pragma unroll
  for (int t = 0; t < 3; ++t) {
    float2 v0 = hp2a[t], v1 = hp2a[t + 3], v2 = hp2b[t], v3 = hp2b[t + 3];
    h00[2 * t] = v0.x; h00[2 * t + 1] = v0.y;
    h01[2 * t] = v1.x; h01[2 * t + 1] = v1.y;
    h10[2 * t] = v2.x; h10[2 * t + 1] = v2.y;
    h11[2 * t] = v3.x; h11[2 * t + 1] = v3.y;
  }

  float P23[40];
#pragma unroll
  for (int a = 0; a < 6; ++a)
#pragma unroll
    for (int d = 0; d < 6; ++d) P23[a * 6 + d] = h10[a] * h11[d];
#pragma unroll
  for (int n = 36; n < 40; ++n) P23[n] = 0.0f;

  floatx4 acc0 = {0.f, 0.f, 0.f, 0.f};
  floatx4 acc1 = {0.f, 0.f, 0.f, 0.f};
  const unsigned short* bp = Bs + lane * 8;
#pragma unroll 1
  for (int d = 0; d < 9; ++d) {  // c = 5d + e; m = 9q + d
    const int m = 9 * q + d;
    const int ia = (m * 43) >> 8;  // m/6 exact for m < 54
    const int ic = m - ia * 6;
    const float p01 = sel6(h00, ia) * sel6(h01, ic);
    const unsigned short* bpd = bp + d * 5 * 512;
#pragma unroll
    for (int e = 0; e < 5; ++e) {
      Frag bf;
      bf.i = *(const intx4*)(bpd + e * 512);
      const int n0 = 8 * e;
      Frag af;
      af.i.x = pk_bf16(p01 * P23[n0 + 0], p01 * P23[n0 + 1]);
      af.i.y = pk_bf16(p01 * P23[n0 + 2], p01 * P23[n0 + 3]);
      af.i.z = pk_bf16(p01 * P23[n0 + 4], p01 * P23[n0 + 5]);
      af.i.w = pk_bf16(p01 * P23[n0 + 6], p01 * P23[n0 + 7]);
      if (e & 1)
        acc1 = __builtin_amdgcn_mfma_f32_16x16x32_bf16(af.s, bf.s, acc1, 0, 0, 0);
      else
        acc0 = __builtin_amdgcn_mfma_f32_16x16x32_bf16(af.s, bf.s, acc0, 0, 0, 0);
    }
  }
  const floatx4 acc = acc0 + acc1;
  if (col < 10) {
#pragma unroll
    for (int r = 0; r < 4; ++r)
      flat[(wave * 16 + q * 4 + r) * 10 + col] = acc[r];
  }
}

// ---------------------------------------------------------------------------
// Linear, split over f: grid (128, 5). Block-reduce + one atomicAdd per o.
// out zero-initialized by prep_kernel.
// ---------------------------------------------------------------------------
__global__ __launch_bounds__(256) void linear_kernel(
    const float* __restrict__ flat, const float* __restrict__ W,
    const float* __restrict__ bias, float* __restrict__ out) {
  const int b = blockIdx.x;
  const int c = blockIdx.y;  // 0..4
  const float* fb = flat + b * 6250 + c * 1250;
  const float* Wc = W + c * 1250;
  float acc[10];
#pragma unroll
  for (int o = 0; o < 10; ++o) acc[o] = 0.0f;
  for (int f = threadIdx.x; f < 1250; f += 256) {
    const float v = fb[f];
#pragma unroll
    for (int o = 0; o < 10; ++o) acc[o] += v * Wc[o * 6250 + f];
  }
#pragma unroll
  for (int o = 0; o < 10; ++o) {
#pragma unroll
    for (int s = 32; s > 0; s >>= 1) acc[o] += __shfl_xor(acc[o], s, 64);
  }
  __shared__ float red[4][10];
  const int lane = threadIdx.x & 63, wv = threadIdx.x >> 6;
  if (lane == 0) {
#pragma unroll
    for (int o = 0; o < 10; ++o) red[wv][o] = acc[o];
  }
  __syncthreads();
  if (threadIdx.x < 10) {
    const int o = threadIdx.x;
    float r = red[0][o] + red[1][o] + red[2][o] + red[3][o];
    if (c == 0) r += bias[o];
    atomicAdd(&out[b * 10 + o], r);
  }
}

// ---------------------------------------------------------------------------
extern "C" void kernel_launch(void* const* d_in, const int* in_sizes, int n_in,
                              void* d_out, int out_size, void* d_ws,
                              size_t ws_size, hipStream_t stream) {
  const float* x = (const float*)d_in[0];     // (128,28,28,2)
  const float* eps0 = (const float*)d_in[1];  // (6,512)
  const float* eps1 = (const float*)d_in[2];  // (10,1296)
  const float* W = (const float*)d_in[3];     // (10,6250)
  const float* bias = (const float*)d_in[4];  // (10,)
  float* out = (float*)d_out;                 // (128,10)

  char* wsb = (char*)d_ws;
  unsigned short* bsw1 = (unsigned short*)wsb;            // 16384 B
  unsigned short* bsw2 = (unsigned short*)(wsb + 16384);  // 46080 B
  float* h = (float*)(wsb + 65536);               // 519168 floats
  float* flat = (float*)(wsb + 65536 + 2076672);  // 800000 floats

  hipLaunchKernelGGL(prep_kernel, dim3(122), dim3(256), 0, stream, eps0, eps1,
                     bsw1, bsw2, out);
  hipLaunchKernelGGL(stage1_mfma, dim3(1352), dim3(256), 0, stream, x, bsw1,
                     h);
  hipLaunchKernelGGL(stage2_mfma, dim3(1250), dim3(256), 0, stream, h, bsw2,
                     flat);
  hipLaunchKernelGGL(linear_kernel, dim3(128, 5), dim3(256), 0, stream, flat,
                     W, bias, out);
}

// Round 6
// 105.088 us; speedup vs baseline: 1.1485x; 1.1485x over previous
//
#include <hip/hip_runtime.h>
#include <hip/hip_bf16.h>
#include <stdint.h>

typedef __attribute__((ext_vector_type(8))) short short8;
typedef __attribute__((ext_vector_type(4))) float floatx4;
typedef __attribute__((ext_vector_type(4))) int intx4;

// ---------------------------------------------------------------------------
// Threefry-2x32 (20 rounds), bit-exact vs JAX (verified r2: absmax 0.0).
// ---------------------------------------------------------------------------
__device__ __forceinline__ void threefry2x32(uint32_t k0, uint32_t k1,
                                             uint32_t& x0, uint32_t& x1) {
  const uint32_t ks2 = k0 ^ k1 ^ 0x1BD11BDAu;
  uint32_t ks[3] = {k0, k1, ks2};
  const int rot[8] = {13, 15, 26, 6, 17, 29, 16, 24};
  x0 += ks[0];
  x1 += ks[1];
#pragma unroll
  for (int i = 0; i < 5; ++i) {
#pragma unroll
    for (int j = 0; j < 4; ++j) {
      const int r = rot[(i & 1) * 4 + j];
      x0 += x1;
      x1 = (x1 << r) | (x1 >> (32 - r));
      x1 ^= x0;
    }
    x0 += ks[(i + 1) % 3];
    x1 += ks[(i + 2) % 3] + (uint32_t)(i + 1);
  }
}

__device__ __forceinline__ float dropmask(int core, int e, float v) {
  uint32_t f0 = 0u, f1 = (uint32_t)core;
  threefry2x32(0u, 42u, f0, f1);
  uint32_t a = 0u, b = (uint32_t)e;
  threefry2x32(f0, f1, a, b);
  uint32_t bits = a ^ b;
  float u = __uint_as_float((bits >> 9) | 0x3F800000u) - 1.0f;
  float m = (u < 0.8f) ? 1.0f : 0.0f;
  return v * m / 0.8f;
}

__device__ __forceinline__ unsigned short f2bf(float f) {  // RNE
  uint32_t u = __float_as_uint(f);
  uint32_t r = u + 0x7fffu + ((u >> 16) & 1u);
  return (unsigned short)(r >> 16);
}

union B2I { __hip_bfloat162 b; int i; };
__device__ __forceinline__ int pk_bf16(float lo, float hi) {
  B2I u;
  u.b = __float22bfloat162_rn(make_float2(lo, hi));
  return u.i;
}
union Frag { intx4 i; short8 s; };

// ---------------------------------------------------------------------------
// Prep: masked bf16 B matrices, pre-swizzled into MFMA B-fragment order
// (verified r3-r5). stage1: k = c*32+q*8+j (c<16). stage2: t=45q+c, m=t/5,
// nk=8*(t%5)+j (c<45, K'=1440, zeros for nk>=36 or invalid col).
// Also zero-inits out (linear_kernel accumulates with atomics).
// ---------------------------------------------------------------------------
__global__ void prep_kernel(const float* __restrict__ eps0,
                            const float* __restrict__ eps1,
                            unsigned short* __restrict__ bsw1,
                            unsigned short* __restrict__ bsw2,
                            float* __restrict__ out) {
  int idx = blockIdx.x * 256 + threadIdx.x;  // grid exactly 31232
  if (idx < 1280) out[idx] = 0.0f;
  if (idx < 8192) {
    int j = idx & 7, L = (idx >> 3) & 63, c = idx >> 9;
    int o = L & 15, q = L >> 4;
    int k = c * 32 + q * 8 + j;
    float v = 0.0f;
    if (o < 6) {
      int e = o * 512 + k;
      v = dropmask(0, e, eps0[e]);
    }
    bsw1[idx] = f2bf(v);
  } else {
    int t2 = idx - 8192;  // < 23040 = 45*512
    int j = t2 & 7, L = (t2 >> 3) & 63, c = t2 >> 9;
    int o = L & 15, q = L >> 4;
    int t = 45 * q + c;
    int m = t / 5, nk = 8 * (t % 5) + j;
    float v = 0.0f;
    if (o < 10 && nk < 36) {
      int e = o * 1296 + m * 36 + nk;
      v = dropmask(1, e, eps1[e]);
    }
    bsw2[t2] = f2bf(v);
  }
}

// 6-way select, cndmask chain (runtime k, constant element indices)
__device__ __forceinline__ float sel6(const float a[6], int k) {
  float r = a[0];
  r = (k == 1) ? a[1] : r;
  r = (k == 2) ? a[2] : r;
  r = (k == 3) ? a[3] : r;
  r = (k == 4) ? a[4] : r;
  r = (k == 5) ? a[5] : r;
  return r;
}

// ---------------------------------------------------------------------------
// Stage 1 via MFMA, B staged in LDS (16 KB, native intx4 array). K-loop
// fully unrolled, 16 chunks; A rebuilt per chunk from t01/t23/w3 (16 regs).
// ---------------------------------------------------------------------------
__global__ __launch_bounds__(256, 2) void stage1_mfma(
    const float* __restrict__ x, const unsigned short* __restrict__ bsw1,
    float* __restrict__ h) {
  __shared__ intx4 Bs[1024];  // chunk c: Bs[c*64 + lane]
  {
    const intx4* src = (const intx4*)bsw1;
#pragma unroll
    for (int t = 0; t < 4; ++t)
      Bs[threadIdx.x + 256 * t] = src[threadIdx.x + 256 * t];
  }
  __syncthreads();

  const int lane = threadIdx.x & 63;
  const int wave = (blockIdx.x * 256 + threadIdx.x) >> 6;  // 0..5407
  const int col = lane & 15, q = lane >> 4;
  const int pid = wave * 16 + col;
  const int b = pid / 676;
  const int rem = pid - b * 676;
  const int ii = rem / 26;
  const int jj = rem - ii * 26;

  const float2* x2 = (const float2*)x;
  float xv[9][2];
#pragma unroll
  for (int di = 0; di < 3; ++di)
#pragma unroll
    for (int dj = 0; dj < 3; ++dj) {
      float2 v = x2[(b * 28 + ii + di) * 28 + (jj + dj)];
      xv[di * 3 + dj][0] = v.x;
      xv[di * 3 + dj][1] = v.y;
    }

  float w3[8];
#pragma unroll
  for (int j = 0; j < 8; ++j)
    w3[j] = xv[6][(j >> 2) & 1] * xv[7][(j >> 1) & 1] * xv[8][j & 1];

  // chunk c -> u = 4c+q: c bits -> pixels 0..3, q bits -> pixels 4,5
  const float wq = xv[4][(q >> 1) & 1] * xv[5][q & 1];
  float t01[4], t23[4];
#pragma unroll
  for (int a = 0; a < 2; ++a)
#pragma unroll
    for (int d = 0; d < 2; ++d) {
      t01[a * 2 + d] = xv[0][a] * xv[1][d];
      t23[a * 2 + d] = xv[2][a] * xv[3][d] * wq;
    }

  floatx4 acc0 = {0.f, 0.f, 0.f, 0.f};
  floatx4 acc1 = {0.f, 0.f, 0.f, 0.f};
#pragma unroll
  for (int c = 0; c < 16; ++c) {
    Frag bf;
    bf.i = Bs[c * 64 + lane];
    const float w = t01[c >> 2] * t23[c & 3];  // compile-time indices
    float av[8];
#pragma unroll
    for (int j = 0; j < 8; ++j) av[j] = w * w3[j];
    Frag af;
    af.i.x = pk_bf16(av[0], av[1]);
    af.i.y = pk_bf16(av[2], av[3]);
    af.i.z = pk_bf16(av[4], av[5]);
    af.i.w = pk_bf16(av[6], av[7]);
    if (c & 1)
      acc1 = __builtin_amdgcn_mfma_f32_16x16x32_bf16(af.s, bf.s, acc1, 0, 0, 0);
    else
      acc0 = __builtin_amdgcn_mfma_f32_16x16x32_bf16(af.s, bf.s, acc0, 0, 0, 0);
  }
  const floatx4 acc = acc0 + acc1;
  if (col < 6) {
#pragma unroll
    for (int r = 0; r < 4; ++r) h[(wave * 16 + q * 4 + r) * 6 + col] = acc[r];
  }
}

// ---------------------------------------------------------------------------
// Stage 2 via MFMA, B staged in LDS (46080 B). K'=1440, fully unrolled.
// No P23[40] array: per outer-d, ph[a] = p01*h10[a] (6 regs); A element
// (n=8e+j) = ph[n/6]*h11[n%6] with compile-time indices -> live aggregate
// is 30 floats, register-resident (kills the r4/r5 scratch spill).
// ---------------------------------------------------------------------------
__global__ __launch_bounds__(256, 2) void stage2_mfma(
    const float* __restrict__ h, const unsigned short* __restrict__ bsw2,
    float* __restrict__ flat) {
  __shared__ intx4 Bs[2880];  // chunk c: Bs[c*64 + lane]
  {
    const intx4* src = (const intx4*)bsw2;
    for (int t = threadIdx.x; t < 2880; t += 256) Bs[t] = src[t];
  }
  __syncthreads();

  const int lane = threadIdx.x & 63;
  const int wave = (blockIdx.x * 256 + threadIdx.x) >> 6;  // 0..4999
  const int col = lane & 15, q = lane >> 4;
  const int pid = wave * 16 + col;
  const int b = pid / 625;
  const int rem = pid - b * 625;
  const int ii = rem / 25;
  const int jj = rem - ii * 25;

  const float* hp = h + ((b * 26 + ii) * 26 + jj) * 6;
  float h00[6], h01[6], h10[6], h11[6];
  const float2* hp2a = (const float2*)(hp);
  const float2* hp2b = (const float2*)(hp + 156);
#pragma unroll
  for (int t = 0; t < 3; ++t) {
    float2 v0 = hp2a[t], v1 = hp2a[t + 3], v2 = hp2b[t], v3 = hp2b[t + 3];
    h00[2 * t] = v0.x; h00[2 * t + 1] = v0.y;
    h01[2 * t] = v1.x; h01[2 * t + 1] = v1.y;
    h10[2 * t] = v2.x; h10[2 * t + 1] = v2.y;
    h11[2 * t] = v3.x; h11[2 * t + 1] = v3.y;
  }

  floatx4 acc0 = {0.f, 0.f, 0.f, 0.f};
  floatx4 acc1 = {0.f, 0.f, 0.f, 0.f};
#pragma unroll
  for (int d = 0; d < 9; ++d) {  // chunk c = 5d + e; m = 9q + d
    const int m = 9 * q + d;
    const int ia = (m * 43) >> 8;  // m/6 exact for m < 54
    const int ic = m - ia * 6;
    const float p01 = sel6(h00, ia) * sel6(h01, ic);
    float ph[6];
#pragma unroll
    for (int a = 0; a < 6; ++a) ph[a] = p01 * h10[a];
#pragma unroll
    for (int e = 0; e < 5; ++e) {
      Frag bf;
      bf.i = Bs[(d * 5 + e) * 64 + lane];
      const int n0 = 8 * e;
      float av[8];
#pragma unroll
      for (int j = 0; j < 8; ++j) {
        const int n = n0 + j;  // < 40; compile-time after unroll
        av[j] = (n < 36) ? ph[n / 6] * h11[n % 6] : 0.0f;
      }
      Frag af;
      af.i.x = pk_bf16(av[0], av[1]);
      af.i.y = pk_bf16(av[2], av[3]);
      af.i.z = pk_bf16(av[4], av[5]);
      af.i.w = pk_bf16(av[6], av[7]);
      if (e & 1)
        acc1 = __builtin_amdgcn_mfma_f32_16x16x32_bf16(af.s, bf.s, acc1, 0, 0, 0);
      else
        acc0 = __builtin_amdgcn_mfma_f32_16x16x32_bf16(af.s, bf.s, acc0, 0, 0, 0);
    }
  }
  const floatx4 acc = acc0 + acc1;
  if (col < 10) {
#pragma unroll
    for (int r = 0; r < 4; ++r)
      flat[(wave * 16 + q * 4 + r) * 10 + col] = acc[r];
  }
}

// ---------------------------------------------------------------------------
// Linear, split over f: grid (128, 5). Block-reduce + one atomicAdd per o.
// out zero-initialized by prep_kernel.
// ---------------------------------------------------------------------------
__global__ __launch_bounds__(256) void linear_kernel(
    const float* __restrict__ flat, const float* __restrict__ W,
    const float* __restrict__ bias, float* __restrict__ out) {
  const int b = blockIdx.x;
  const int c = blockIdx.y;  // 0..4
  const float* fb = flat + b * 6250 + c * 1250;
  const float* Wc = W + c * 1250;
  float acc[10];
#pragma unroll
  for (int o = 0; o < 10; ++o) acc[o] = 0.0f;
  for (int f = threadIdx.x; f < 1250; f += 256) {
    const float v = fb[f];
#pragma unroll
    for (int o = 0; o < 10; ++o) acc[o] += v * Wc[o * 6250 + f];
  }
#pragma unroll
  for (int o = 0; o < 10; ++o) {
#pragma unroll
    for (int s = 32; s > 0; s >>= 1) acc[o] += __shfl_xor(acc[o], s, 64);
  }
  __shared__ float red[4][10];
  const int lane = threadIdx.x & 63, wv = threadIdx.x >> 6;
  if (lane == 0) {
#pragma unroll
    for (int o = 0; o < 10; ++o) red[wv][o] = acc[o];
  }
  __syncthreads();
  if (threadIdx.x < 10) {
    const int o = threadIdx.x;
    float r = red[0][o] + red[1][o] + red[2][o] + red[3][o];
    if (c == 0) r += bias[o];
    atomicAdd(&out[b * 10 + o], r);
  }
}

// ---------------------------------------------------------------------------
extern "C" void kernel_launch(void* const* d_in, const int* in_sizes, int n_in,
                              void* d_out, int out_size, void* d_ws,
                              size_t ws_size, hipStream_t stream) {
  const float* x = (const float*)d_in[0];     // (128,28,28,2)
  const float* eps0 = (const float*)d_in[1];  // (6,512)
  const float* eps1 = (const float*)d_in[2];  // (10,1296)
  const float* W = (const float*)d_in[3];     // (10,6250)
  const float* bias = (const float*)d_in[4];  // (10,)
  float* out = (float*)d_out;                 // (128,10)

  char* wsb = (char*)d_ws;
  unsigned short* bsw1 = (unsigned short*)wsb;            // 16384 B
  unsigned short* bsw2 = (unsigned short*)(wsb + 16384);  // 46080 B
  float* h = (float*)(wsb + 65536);               // 519168 floats
  float* flat = (float*)(wsb + 65536 + 2076672);  // 800000 floats

  hipLaunchKernelGGL(prep_kernel, dim3(122), dim3(256), 0, stream, eps0, eps1,
                     bsw1, bsw2, out);
  hipLaunchKernelGGL(stage1_mfma, dim3(1352), dim3(256), 0, stream, x, bsw1,
                     h);
  hipLaunchKernelGGL(stage2_mfma, dim3(1250), dim3(256), 0, stream, h, bsw2,
                     flat);
  hipLaunchKernelGGL(linear_kernel, dim3(128, 5), dim3(256), 0, stream, flat,
                     W, bias, out);
}